// Round 8
// baseline (145.675 us; speedup 1.0000x reference)
//
#include <hip/hip_runtime.h>
#include <hip/hip_bf16.h>
#include <cstdint>
#include <cstddef>

typedef __attribute__((ext_vector_type(8))) short short8;
typedef __attribute__((ext_vector_type(4))) short s16x4;
typedef __attribute__((ext_vector_type(4))) unsigned short u16x4;
typedef __attribute__((ext_vector_type(4))) float f32x4;
typedef __attribute__((ext_vector_type(4))) unsigned int u32x4;

__device__ __forceinline__ short bfbits(float f) {
    __bf16 h = (__bf16)f;
    return __builtin_bit_cast(short, h);
}
__device__ __forceinline__ float bf2f(unsigned short b) {
    union { uint32_t u; float f; } v; v.u = ((uint32_t)b) << 16;
    return v.f;
}
__device__ __forceinline__ unsigned int pack2(float x, float y) {
    return (unsigned int)(unsigned short)bfbits(x) |
           ((unsigned int)(unsigned short)bfbits(y) << 16);
}

// ---------- kernel 0: weight transpose + bf16 convert (LDS tile) ----------
// wt[mat][n][k] = bf16(W[mat][k][n]),  mat: 0=Wq 1=Wk 2=Wv 3=Wg 4=Wo
__global__ __launch_bounds__(256) void wt_kernel(
    const float* __restrict__ Wq, const float* __restrict__ Wk,
    const float* __restrict__ Wv, const float* __restrict__ Wg,
    const float* __restrict__ Wo, unsigned short* __restrict__ wt)
{
    int mat  = blockIdx.x >> 4;
    int tile = blockIdx.x & 15;
    int k0 = (tile >> 2) * 64, n0 = (tile & 3) * 64;
    const float* W = (mat==0)?Wq:(mat==1)?Wk:(mat==2)?Wv:(mat==3)?Wg:Wo;
    __shared__ unsigned short T[64][72];   // T[n][k]
    int tid = threadIdx.x;
    int tx = tid & 15, ty = tid >> 4;
    #pragma unroll
    for (int j = 0; j < 4; ++j) {
        int kr = ty + j*16;
        f32x4 v = *(const f32x4*)(W + (size_t)(k0+kr)*256 + n0 + tx*4);
        #pragma unroll
        for (int e = 0; e < 4; ++e) T[tx*4+e][kr] = (unsigned short)bfbits(v[e]);
    }
    __syncthreads();
    #pragma unroll
    for (int j = 0; j < 4; ++j) {
        int nr = ty + j*16;
        u16x4 st;
        #pragma unroll
        for (int e = 0; e < 4; ++e) st[e] = T[nr][tx*4+e];
        *(u16x4*)(wt + ((size_t)mat*256 + n0+nr)*256 + k0 + tx*4) = st;
    }
}

// ---------- kernel 0b: bias tiling into MFMA-fragment order ----------
// bt[h][qt][n][ c*16 + g*4 + i ] = bias[h][qt*16 + c][n*16 + 4g + i]  (f32)
__global__ __launch_bounds__(256) void bias_prep_kernel(
    const float* __restrict__ bias, float* __restrict__ bt)
{
    int hb = blockIdx.x;        // 0..127 = h*16 + qt
    int h = hb >> 4, qt = hb & 15;
    int tid = threadIdx.x;
    int cc = tid >> 4, n = tid & 15;
    const float* src = bias + ((size_t)(h*256 + qt*16 + cc))*256 + n*16;
    float* dst = bt + ((size_t)(hb*16 + n))*256 + cc*16;
    #pragma unroll
    for (int q = 0; q < 4; ++q)
        *(f32x4*)(dst + q*4) = *(const f32x4*)(src + q*4);
}

// ---------- unified proj wave-loop over a 32-row swizzled LDS tile ----------
// Xs: [32 rows][256 k] bf16, row stride 512 B, byte-col XOR ((row&31)<<4).
// SWAP=1: acc[m][n] = mfma(b[n], a[m], .)  -> D[row=w_col][col=x_row]
// SWAP=0: acc[m][n] = mfma(a[m], b[n], .)  -> D[row=x_row][col=w_col]
template<int SWAP>
__device__ __forceinline__ void unified_loop(
    const unsigned short* Xs, const unsigned short* Wt,
    int col0, int c, int g, f32x4 acc[2][4])
{
    short8 pb[4];
    #pragma unroll
    for (int n = 0; n < 4; ++n)
        pb[n] = *(const short8*)(Wt + (size_t)(col0 + n*16 + c) * 256 + g*8);

    #pragma unroll
    for (int step = 0; step < 8; ++step) {
        short8 b[4];
        #pragma unroll
        for (int n = 0; n < 4; ++n) b[n] = pb[n];
        if (step < 7) {
            int koff = (step + 1) * 32 + g * 8;
            #pragma unroll
            for (int n = 0; n < 4; ++n)
                pb[n] = *(const short8*)(Wt + (size_t)(col0 + n*16 + c) * 256 + koff);
        }
        short8 a[2];
        #pragma unroll
        for (int m = 0; m < 2; ++m) {
            int row = m * 16 + c;
            int off = row * 512 + ((step * 64 + g * 16) ^ ((row & 31) << 4));
            a[m] = *(const short8*)((const char*)Xs + off);
        }
        #pragma unroll
        for (int m = 0; m < 2; ++m)
            #pragma unroll
            for (int n = 0; n < 4; ++n) {
                if (SWAP)
                    acc[m][n] = __builtin_amdgcn_mfma_f32_16x16x32_bf16(b[n], a[m], acc[m][n], 0, 0, 0);
                else
                    acc[m][n] = __builtin_amdgcn_mfma_f32_16x16x32_bf16(a[m], b[n], acc[m][n], 0, 0, 0);
            }
    }
}

// ---------- kernel 1: unified projections ----------
// One block per 32-row slab (grid 1024). Stage qx/kx/vx slabs once.
// Waves 0-3: Q then G (qx tile, swapped). Waves 4-7: K (swapped) then V (unswapped).
__global__ __launch_bounds__(512, 4) void proj_kernel(
    const float* __restrict__ qx, const float* __restrict__ kx, const float* __restrict__ vx,
    const float* __restrict__ bg, const unsigned short* __restrict__ wt,
    unsigned short* __restrict__ Qa, unsigned short* __restrict__ Ka,
    unsigned short* __restrict__ Va, unsigned short* __restrict__ G)
{
    __shared__ __align__(16) unsigned short Xs[3][32 * 256];   // 48 KB

    int row0 = blockIdx.x * 32;
    int tid = threadIdx.x;
    int w = tid >> 6, lane = tid & 63;
    int c = lane & 15, g = lane >> 4;
    int col0 = (w & 3) * 64;

    // ---- stage all three 32x256 slabs as bf16, swizzled ----
    {
        int srow = tid >> 4;            // 0..31
        int scol = (tid & 15) * 16;     // float index
        int bc   = scol * 2;            // byte col
        int sw   = (srow & 31) << 4;
        #pragma unroll
        for (int s = 0; s < 3; ++s) {
            const float* X = (s == 0) ? qx : (s == 1) ? kx : vx;
            const float* src = X + (size_t)(row0 + srow) * 256 + scol;
            f32x4 x0 = *(const f32x4*)(src + 0);
            f32x4 x1 = *(const f32x4*)(src + 4);
            f32x4 x2 = *(const f32x4*)(src + 8);
            f32x4 x3 = *(const f32x4*)(src + 12);
            u32x4 w0, w1;
            w0[0]=pack2(x0[0],x0[1]); w0[1]=pack2(x0[2],x0[3]);
            w0[2]=pack2(x1[0],x1[1]); w0[3]=pack2(x1[2],x1[3]);
            w1[0]=pack2(x2[0],x2[1]); w1[1]=pack2(x2[2],x2[3]);
            w1[2]=pack2(x3[0],x3[1]); w1[3]=pack2(x3[2],x3[3]);
            char* base = (char*)&Xs[s][0] + srow * 512;
            *(u32x4*)(base + ((bc)      ^ sw)) = w0;
            *(u32x4*)(base + ((bc + 16) ^ sw)) = w1;
        }
    }
    __syncthreads();

    int r_ = row0 >> 8;
    int s0b = row0 & 255;
    f32x4 acc[2][4];

    // ---- loop A: Q (waves 0-3) or K (waves 4-7), both swapped ----
    #pragma unroll
    for (int m = 0; m < 2; ++m)
        #pragma unroll
        for (int n = 0; n < 4; ++n) acc[m][n] = 0.0f;

    const unsigned short* XsA = (w < 4) ? &Xs[0][0] : &Xs[1][0];
    const unsigned short* WtA = (w < 4) ? wt : wt + 65536;
    unified_loop<1>(XsA, WtA, col0, c, g, acc);

    {
        unsigned short* dst = (w < 4) ? Qa : Ka;
        #pragma unroll
        for (int n = 0; n < 4; ++n) {
            int colb = col0 + n * 16 + 4 * g;
            int h_ = colb >> 5, d0 = colb & 31;
            #pragma unroll
            for (int m = 0; m < 2; ++m) {
                int s_ = s0b + m * 16 + c;
                u16x4 st;
                #pragma unroll
                for (int i = 0; i < 4; ++i) st[i] = (unsigned short)bfbits(acc[m][n][i]);
                *(u16x4*)(dst + ((size_t)((r_*8 + h_)*256 + s_)) * 32 + d0) = st;
            }
        }
    }

    // ---- loop B: G (waves 0-3, swapped) or V (waves 4-7, unswapped) ----
    #pragma unroll
    for (int m = 0; m < 2; ++m)
        #pragma unroll
        for (int n = 0; n < 4; ++n) acc[m][n] = 0.0f;

    if (w < 4) {
        unified_loop<1>(&Xs[0][0], wt + 3*65536, col0, c, g, acc);
        #pragma unroll
        for (int n = 0; n < 4; ++n) {
            int colb = col0 + n * 16 + 4 * g;
            f32x4 bgv = *(const f32x4*)(bg + colb);
            #pragma unroll
            for (int m = 0; m < 2; ++m) {
                int rq = row0 + m * 16 + c;
                u16x4 st;
                #pragma unroll
                for (int i = 0; i < 4; ++i) {
                    float s = 1.0f / (1.0f + __expf(-(acc[m][n][i] + bgv[i])));
                    st[i] = (unsigned short)bfbits(s);
                }
                *(u16x4*)(G + (size_t)rq * 256 + colb) = st;
            }
        }
    } else {
        unified_loop<0>(&Xs[2][0], wt + 2*65536, col0, c, g, acc);
        #pragma unroll
        for (int m = 0; m < 2; ++m) {
            int s0 = s0b + m * 16 + 4 * g;
            #pragma unroll
            for (int n = 0; n < 4; ++n) {
                int dcol = col0 + n * 16 + c;
                int h_ = dcol >> 5, d_ = dcol & 31;
                u16x4 st;
                #pragma unroll
                for (int i = 0; i < 4; ++i) st[i] = (unsigned short)bfbits(acc[m][n][i]);
                *(u16x4*)(Va + ((size_t)((r_*8 + h_)*32 + d_)) * 256 + s0) = st;
            }
        }
    }
}

// ---------- kernel 2: attention, one block per (r,h), K/V in LDS ----------
// Swapped QK^T (lane owns q-row), online exp (no max-sub), PV swapped
// (mfma(V,P)) so 1/rowsum is lane-local and epilogue is d-major u16x4.
__global__ __launch_bounds__(512) void attn_kernel(
    const unsigned short* __restrict__ Qa, const unsigned short* __restrict__ Ka,
    const unsigned short* __restrict__ Va, const unsigned short* __restrict__ G,
    const float* __restrict__ bt, unsigned short* __restrict__ og)
{
    __shared__ __align__(16) unsigned short Ks[256 * 40];  // [s][d] pad 40
    __shared__ __align__(16) unsigned short Vs[32 * 264];  // [d][k-permuted] pad 264

    int rh = blockIdx.x;            // 0..1023
    int r = rh >> 3, h = rh & 7;
    int tid = threadIdx.x;          // 512 threads
    int w = tid >> 6, lane = tid & 63;
    int c = lane & 15, g = lane >> 4;
    size_t base = (size_t)rh * 8192;

    // stage K coalesced: 2 passes x 512 threads x 16B
    #pragma unroll
    for (int j = 0; j < 2; ++j) {
        int idx8 = (tid + j*512) * 8;
        int s_ = idx8 >> 5, d_ = idx8 & 31;
        short8 v = *(const short8*)(Ka + base + idx8);
        *(short8*)(&Ks[s_*40 + d_]) = v;
    }
    // stage V^T with k-slot permutation within each 32-k block:
    // position p = g*8 + m + 4b  <->  k = 32t + 4g + m + 16b
    #pragma unroll
    for (int j = 0; j < 2; ++j) {
        int idx8 = (tid + j*512) * 8;
        int d_ = idx8 >> 8, s0 = idx8 & 255;
        short8 v = *(const short8*)(Va + base + idx8);
        int t  = s0 >> 5;
        int ap = (s0 >> 3) & 3;
        int bb = ap >> 1;
        int g1 = (2*ap) & 3, g2 = (2*ap + 1) & 3;
        int p1 = t*32 + g1*8 + 4*bb;
        int p2 = t*32 + g2*8 + 4*bb;
        s16x4 lo, hi;
        lo[0]=v[0]; lo[1]=v[1]; lo[2]=v[2]; lo[3]=v[3];
        hi[0]=v[4]; hi[1]=v[5]; hi[2]=v[6]; hi[3]=v[7];
        *(s16x4*)(&Vs[d_*264 + p1]) = lo;
        *(s16x4*)(&Vs[d_*264 + p2]) = hi;
    }
    __syncthreads();

    const float* bth = bt + (size_t)h * 65536;
    const float nrmv = 0.17677669529663687f;

    #pragma unroll 1
    for (int qq = 0; qq < 2; ++qq) {
        int qt = w*2 + qq;                 // 0..15
        int qrow = qt * 16;
        short8 qf = *(const short8*)(Qa + base + (size_t)(qrow + c)*32 + g*8);
        const float* btt = bth + (size_t)qt*4096 + (c*4 + g)*4;

        f32x4 o0 = 0.0f, o1 = 0.0f;
        float sum = 0.f;
        #pragma unroll
        for (int t = 0; t < 8; ++t) {
            int n0 = 2*t, n1 = 2*t + 1;
            short8 kf0 = *(const short8*)(&Ks[(n0*16 + c)*40 + g*8]);
            short8 kf1 = *(const short8*)(&Ks[(n1*16 + c)*40 + g*8]);
            f32x4 bv0 = *(const f32x4*)(btt + n0*256);
            f32x4 bv1 = *(const f32x4*)(btt + n1*256);
            f32x4 z = 0.0f;
            f32x4 s0 = __builtin_amdgcn_mfma_f32_16x16x32_bf16(kf0, qf, z, 0, 0, 0);
            f32x4 s1 = __builtin_amdgcn_mfma_f32_16x16x32_bf16(kf1, qf, z, 0, 0, 0);
            float e0 = __expf(fmaf(s0[0], nrmv, bv0[0]));
            float e1 = __expf(fmaf(s0[1], nrmv, bv0[1]));
            float e2 = __expf(fmaf(s0[2], nrmv, bv0[2]));
            float e3 = __expf(fmaf(s0[3], nrmv, bv0[3]));
            float e4 = __expf(fmaf(s1[0], nrmv, bv1[0]));
            float e5 = __expf(fmaf(s1[1], nrmv, bv1[1]));
            float e6 = __expf(fmaf(s1[2], nrmv, bv1[2]));
            float e7 = __expf(fmaf(s1[3], nrmv, bv1[3]));
            sum += ((e0+e1)+(e2+e3)) + ((e4+e5)+(e6+e7));
            u32x4 aw;
            aw[0] = pack2(e0, e1); aw[1] = pack2(e2, e3);
            aw[2] = pack2(e4, e5); aw[3] = pack2(e6, e7);
            short8 pfrag = __builtin_bit_cast(short8, aw);
            short8 va0 = *(const short8*)(&Vs[(c)*264      + t*32 + g*8]);
            short8 va1 = *(const short8*)(&Vs[(16 + c)*264 + t*32 + g*8]);
            o0 = __builtin_amdgcn_mfma_f32_16x16x32_bf16(va0, pfrag, o0, 0, 0, 0);
            o1 = __builtin_amdgcn_mfma_f32_16x16x32_bf16(va1, pfrag, o1, 0, 0, 0);
        }
        sum += __shfl_xor(sum, 16);
        sum += __shfl_xor(sum, 32);
        float inv = 1.0f / sum;

        // lane (c,g) holds O[q=qrow+c][d = n2*16 + 4g + i]
        size_t orow = ((size_t)(r*256 + qrow + c)) * 256 + h*32;
        #pragma unroll
        for (int n2 = 0; n2 < 2; ++n2) {
            int d0 = n2*16 + 4*g;
            u16x4 gv = *(const u16x4*)(G + orow + d0);
            f32x4 ov = n2 ? o1 : o0;
            u16x4 st;
            #pragma unroll
            for (int i = 0; i < 4; ++i)
                st[i] = (unsigned short)bfbits(ov[i] * inv * bf2f(gv[i]));
            *(u16x4*)(og + orow + d0) = st;
        }
    }
}

// ---------- oproj K-loop (As: 64x256 swizzled tile, swapped) ----------
__device__ __forceinline__ void proj_mfma_loop_swap(
    const unsigned short* As, const unsigned short* Wt,
    int col0, int c, int g, f32x4 acc[4][4])
{
    short8 pb[4];
    #pragma unroll
    for (int n = 0; n < 4; ++n)
        pb[n] = *(const short8*)(Wt + (size_t)(col0 + n*16 + c) * 256 + g*8);

    #pragma unroll
    for (int step = 0; step < 8; ++step) {
        short8 b[4];
        #pragma unroll
        for (int n = 0; n < 4; ++n) b[n] = pb[n];
        if (step < 7) {
            int koff = (step + 1) * 32 + g * 8;
            #pragma unroll
            for (int n = 0; n < 4; ++n)
                pb[n] = *(const short8*)(Wt + (size_t)(col0 + n*16 + c) * 256 + koff);
        }
        short8 a[4];
        #pragma unroll
        for (int m = 0; m < 4; ++m) {
            int row = m * 16 + c;
            int off = row * 512 + ((step * 64 + g * 16) ^ ((row & 31) << 4));
            a[m] = *(const short8*)((const char*)As + off);
        }
        #pragma unroll
        for (int m = 0; m < 4; ++m)
            #pragma unroll
            for (int n = 0; n < 4; ++n)
                acc[m][n] = __builtin_amdgcn_mfma_f32_16x16x32_bf16(b[n], a[m], acc[m][n], 0, 0, 0);
    }
}

// ---------- kernel 3: output projection (LDS-staged og, swapped MFMA) ----------
__global__ __launch_bounds__(256) void oproj_kernel(
    const unsigned short* __restrict__ og, const unsigned short* __restrict__ wt_o,
    const float* __restrict__ bo, float* __restrict__ out)
{
    __shared__ __align__(16) unsigned short As[64 * 256];

    int row0 = blockIdx.x * 64;
    int tid = threadIdx.x;
    int lane = tid & 63;
    int c = lane & 15, g = lane >> 4;
    int col0 = (tid >> 6) * 64;

    // stage og tile (bf16 already), swizzled
    #pragma unroll
    for (int j = 0; j < 8; ++j) {
        int idx = tid * 8 + j * 2048;
        int row = idx >> 8;
        int colB = (idx & 255) * 2;
        short8 v = *(const short8*)(og + (size_t)(row0 + row) * 256 + (idx & 255));
        int off = row * 512 + (colB ^ ((row & 31) << 4));
        *(short8*)((char*)As + off) = v;
    }
    __syncthreads();

    f32x4 acc[4][4];
    #pragma unroll
    for (int m = 0; m < 4; ++m)
        #pragma unroll
        for (int n = 0; n < 4; ++n)
            acc[m][n] = 0.0f;

    proj_mfma_loop_swap(As, wt_o, col0, c, g, acc);

    #pragma unroll
    for (int n = 0; n < 4; ++n) {
        int colb = col0 + n * 16 + 4 * g;
        f32x4 bov = *(const f32x4*)(bo + colb);
        #pragma unroll
        for (int m = 0; m < 4; ++m) {
            int row = row0 + m * 16 + c;
            f32x4 st = acc[m][n] + bov;
            *(f32x4*)(out + (size_t)row * 256 + colb) = st;
        }
    }
}

extern "C" void kernel_launch(void* const* d_in, const int* in_sizes, int n_in,
                              void* d_out, int out_size, void* d_ws, size_t ws_size,
                              hipStream_t stream) {
    const float* qx   = (const float*)d_in[0];
    const float* kx   = (const float*)d_in[1];
    const float* vx   = (const float*)d_in[2];
    const float* bias = (const float*)d_in[3];
    const float* Wq   = (const float*)d_in[4];
    const float* Wk   = (const float*)d_in[5];
    const float* Wv   = (const float*)d_in[6];
    const float* Wo   = (const float*)d_in[7];
    const float* bo   = (const float*)d_in[8];
    const float* Wg   = (const float*)d_in[9];
    const float* bg   = (const float*)d_in[10];

    uint8_t* ws = (uint8_t*)d_ws;
    unsigned short* wt = (unsigned short*)ws;                         // 640 KB
    unsigned short* Qa = (unsigned short*)(ws + (1u<<20));
    unsigned short* Ka = (unsigned short*)(ws + (1u<<20) + 1u*(1u<<24));
    unsigned short* Va = (unsigned short*)(ws + (1u<<20) + 2u*(1u<<24));
    unsigned short* G  = (unsigned short*)(ws + (1u<<20) + 3u*(1u<<24));
    unsigned short* og = (unsigned short*)(ws + (1u<<20) + 4u*(1u<<24));
    float*          bt = (float*)        (ws + (1u<<20) + 5u*(1u<<24)); // 2 MB

    hipLaunchKernelGGL(wt_kernel, dim3(80), dim3(256), 0, stream, Wq, Wk, Wv, Wg, Wo, wt);
    hipLaunchKernelGGL(bias_prep_kernel, dim3(128), dim3(256), 0, stream, bias, bt);
    hipLaunchKernelGGL(proj_kernel, dim3(1024), dim3(512), 0, stream, qx, kx, vx, bg, wt, Qa, Ka, Va, G);
    hipLaunchKernelGGL(attn_kernel, dim3(1024), dim3(512), 0, stream, Qa, Ka, Va, G, bt, og);
    hipLaunchKernelGGL(oproj_kernel, dim3(512), dim3(256), 0, stream, og, wt + 4*65536, bo, (float*)d_out);
}

// Round 9
// 120.878 us; speedup vs baseline: 1.2051x; 1.2051x over previous
//
#include <hip/hip_runtime.h>
#include <hip/hip_bf16.h>
#include <cstdint>
#include <cstddef>

typedef __attribute__((ext_vector_type(8))) short short8;
typedef __attribute__((ext_vector_type(4))) short s16x4;
typedef __attribute__((ext_vector_type(4))) unsigned short u16x4;
typedef __attribute__((ext_vector_type(8))) unsigned short u16x8;
typedef __attribute__((ext_vector_type(4))) float f32x4;
typedef __attribute__((ext_vector_type(4))) unsigned int u32x4;

__device__ __forceinline__ short bfbits(float f) {
    __bf16 h = (__bf16)f;
    return __builtin_bit_cast(short, h);
}
__device__ __forceinline__ float bf2f(unsigned short b) {
    union { uint32_t u; float f; } v; v.u = ((uint32_t)b) << 16;
    return v.f;
}
__device__ __forceinline__ unsigned int pack2(float x, float y) {
    return (unsigned int)(unsigned short)bfbits(x) |
           ((unsigned int)(unsigned short)bfbits(y) << 16);
}

// ---------- kernel 0: weight transpose + bias tiling (merged prep) ----------
// blocks 0..79: wt[mat][n][k'] = bf16(W[mat][k][n]); mat4 (Wo) gets sigma-permuted k.
// blocks 80..207: bias -> bt MFMA-fragment tiling.
__global__ __launch_bounds__(256) void prep_kernel(
    const float* __restrict__ Wq, const float* __restrict__ Wk,
    const float* __restrict__ Wv, const float* __restrict__ Wg,
    const float* __restrict__ Wo, unsigned short* __restrict__ wt,
    const float* __restrict__ bias, float* __restrict__ bt)
{
    int bid = blockIdx.x;
    int tid = threadIdx.x;
    if (bid < 80) {
        int mat  = bid >> 4;
        int tile = bid & 15;
        int k0 = (tile >> 2) * 64, n0 = (tile & 3) * 64;
        const float* W = (mat==0)?Wq:(mat==1)?Wk:(mat==2)?Wv:(mat==3)?Wg:Wo;
        __shared__ unsigned short T[64][72];   // T[n][k]
        int tx = tid & 15, ty = tid >> 4;
        #pragma unroll
        for (int j = 0; j < 4; ++j) {
            int kr = ty + j*16;
            f32x4 v = *(const f32x4*)(W + (size_t)(k0+kr)*256 + n0 + tx*4);
            #pragma unroll
            for (int e = 0; e < 4; ++e) T[tx*4+e][kr] = (unsigned short)bfbits(v[e]);
        }
        __syncthreads();
        #pragma unroll
        for (int j = 0; j < 4; ++j) {
            int nr = ty + j*16;
            int kk = k0 + tx*4;
            int dstk = kk;
            if (mat == 4) {
                // sigma within each 32-block of k: 4a+e -> 8a+e (a<4), 16+4g+e -> 8g+4+e
                int a = (kk >> 2) & 7;
                int hb = kk & ~31;
                dstk = hb + ((a < 4) ? 8*a : 8*(a-4) + 4);
            }
            u16x4 st;
            #pragma unroll
            for (int e = 0; e < 4; ++e) st[e] = T[nr][tx*4+e];
            *(u16x4*)(wt + ((size_t)mat*256 + n0+nr)*256 + dstk) = st;
        }
    } else {
        int hb = bid - 80;          // 0..127 = h*16 + qt
        int h = hb >> 4, qt = hb & 15;
        int cc = tid >> 4, n = tid & 15;
        const float* src = bias + ((size_t)(h*256 + qt*16 + cc))*256 + n*16;
        float* dst = bt + ((size_t)(hb*16 + n))*256 + cc*16;
        #pragma unroll
        for (int q = 0; q < 4; ++q)
            *(f32x4*)(dst + q*4) = *(const f32x4*)(src + q*4);
    }
}

// ---------- proj K-loop (templated on operand order), R6 structure ----------
// As: 64x256 bf16 tile, row stride 512 B, byte-col XOR ((row&31)<<4).
template<int SWAP>
__device__ __forceinline__ void proj_mfma_loop(
    const unsigned short* As, const unsigned short* Wt,
    int col0, int c, int g, f32x4 acc[4][4])
{
    short8 pb[4];
    #pragma unroll
    for (int n = 0; n < 4; ++n)
        pb[n] = *(const short8*)(Wt + (size_t)(col0 + n*16 + c) * 256 + g*8);

    #pragma unroll
    for (int step = 0; step < 8; ++step) {
        short8 b[4];
        #pragma unroll
        for (int n = 0; n < 4; ++n) b[n] = pb[n];
        if (step < 7) {
            int koff = (step + 1) * 32 + g * 8;
            #pragma unroll
            for (int n = 0; n < 4; ++n)
                pb[n] = *(const short8*)(Wt + (size_t)(col0 + n*16 + c) * 256 + koff);
        }
        short8 a[4];
        #pragma unroll
        for (int m = 0; m < 4; ++m) {
            int row = m * 16 + c;
            int off = row * 512 + ((step * 64 + g * 16) ^ ((row & 31) << 4));
            a[m] = *(const short8*)((const char*)As + off);
        }
        #pragma unroll
        for (int m = 0; m < 4; ++m)
            #pragma unroll
            for (int n = 0; n < 4; ++n) {
                if (SWAP)
                    acc[m][n] = __builtin_amdgcn_mfma_f32_16x16x32_bf16(b[n], a[m], acc[m][n], 0, 0, 0);
                else
                    acc[m][n] = __builtin_amdgcn_mfma_f32_16x16x32_bf16(a[m], b[n], acc[m][n], 0, 0, 0);
            }
    }
}

// ---------- kernel 1: projections, R6 block structure, 3 types ----------
// type 0: qx -> Q then G (both swapped). type 1: kx -> K. type 2: vx -> V (unswapped).
// Qa/Ka: [rh][s][d'] with d' = sigma(d). Va: [rh][d][s'] with s' = tau(s).
// G: [rq][h*32+sigma(d)].
__global__ __launch_bounds__(256) void proj_kernel(
    const float* __restrict__ qx, const float* __restrict__ kx, const float* __restrict__ vx,
    const float* __restrict__ bg, const unsigned short* __restrict__ wt,
    unsigned short* __restrict__ Qa, unsigned short* __restrict__ Ka,
    unsigned short* __restrict__ Va, unsigned short* __restrict__ G)
{
    __shared__ __align__(16) unsigned short As[64 * 256]; // bf16 X-tile, swizzled

    int bx = blockIdx.x;
    int typ = bx % 3;
    int rb  = bx / 3;
    int row0 = rb * 64;
    int tid = threadIdx.x;
    int lane = tid & 63;
    int c = lane & 15, g = lane >> 4;
    int col0 = (tid >> 6) * 64;

    const float* X = (typ == 0) ? qx : (typ == 1) ? kx : vx;

    // ---- stage X tile (64 rows x 256 k) as bf16, swizzled (R6 pattern) ----
    {
        int l32 = tid & 31;
        int rg  = tid >> 5;
        #pragma unroll
        for (int j = 0; j < 8; ++j) {
            int row = j * 8 + rg;
            const float* src = X + (size_t)(row0 + row) * 256 + l32 * 8;
            f32x4 lo = *(const f32x4*)src;
            f32x4 hi = *(const f32x4*)(src + 4);
            u32x4 pkv;
            pkv[0] = pack2(lo[0], lo[1]); pkv[1] = pack2(lo[2], lo[3]);
            pkv[2] = pack2(hi[0], hi[1]); pkv[3] = pack2(hi[2], hi[3]);
            int off = row * 512 + ((l32 * 16) ^ ((row & 31) << 4));
            *(u32x4*)((char*)As + off) = pkv;
        }
    }
    __syncthreads();

    int r_ = row0 >> 8;
    int s0b = row0 & 255;

    f32x4 acc[4][4];
    #pragma unroll
    for (int m = 0; m < 4; ++m)
        #pragma unroll
        for (int n = 0; n < 4; ++n) acc[m][n] = 0.0f;

    if (typ == 2) {
        // V: unswapped. acc[m][n]: s = s0b+m*16+4g+i, d = col0+n*16+c
        proj_mfma_loop<0>(As, wt + 2*65536, col0, c, g, acc);
        #pragma unroll
        for (int n = 0; n < 4; ++n) {
            int dcol = col0 + n * 16;
            int h_ = dcol >> 5, d_ = (dcol & 31) + c;
            size_t rowbase = ((size_t)((r_*8 + h_)*32 + d_)) * 256;
            #pragma unroll
            for (int p = 0; p < 2; ++p) {     // m-pairs (0,1),(2,3)
                u16x8 st;
                #pragma unroll
                for (int i = 0; i < 4; ++i) {
                    st[i]     = (unsigned short)bfbits(acc[2*p][n][i]);
                    st[i + 4] = (unsigned short)bfbits(acc[2*p+1][n][i]);
                }
                *(u16x8*)(Va + rowbase + s0b + 32*p + 8*g) = st;
            }
        }
    } else {
        // loop A: Q (typ 0) or K (typ 1), swapped. acc: row = col0+n*16+4g+i, col = s0b+m*16+c
        const unsigned short* WtA = (typ == 0) ? wt : wt + 65536;
        proj_mfma_loop<1>(As, WtA, col0, c, g, acc);
        unsigned short* dst = (typ == 0) ? Qa : Ka;
        #pragma unroll
        for (int np = 0; np < 2; ++np) {      // n-pairs (0,1),(2,3)
            int n0 = 2 * np;
            int h_ = (col0 + n0*16) >> 5;
            #pragma unroll
            for (int m = 0; m < 4; ++m) {
                int s_ = s0b + m * 16 + c;
                u16x8 st;
                #pragma unroll
                for (int i = 0; i < 4; ++i) {
                    st[i]     = (unsigned short)bfbits(acc[m][n0][i]);
                    st[i + 4] = (unsigned short)bfbits(acc[m][n0+1][i]);
                }
                *(u16x8*)(dst + ((size_t)((r_*8 + h_)*256 + s_)) * 32 + 8*g) = st;
            }
        }

        if (typ == 0) {
            // loop B: G (swapped), reuse staged qx tile
            #pragma unroll
            for (int m = 0; m < 4; ++m)
                #pragma unroll
                for (int n = 0; n < 4; ++n) acc[m][n] = 0.0f;
            proj_mfma_loop<1>(As, wt + 3*65536, col0, c, g, acc);
            #pragma unroll
            for (int np = 0; np < 2; ++np) {
                int n0 = 2 * np;
                int colb = col0 + n0 * 16;
                f32x4 bg0 = *(const f32x4*)(bg + colb + 4*g);
                f32x4 bg1 = *(const f32x4*)(bg + colb + 16 + 4*g);
                #pragma unroll
                for (int m = 0; m < 4; ++m) {
                    int rq = row0 + m * 16 + c;
                    u16x8 st;
                    #pragma unroll
                    for (int i = 0; i < 4; ++i) {
                        float sa = 1.0f / (1.0f + __expf(-(acc[m][n0][i]   + bg0[i])));
                        float sb = 1.0f / (1.0f + __expf(-(acc[m][n0+1][i] + bg1[i])));
                        st[i]     = (unsigned short)bfbits(sa);
                        st[i + 4] = (unsigned short)bfbits(sb);
                    }
                    *(u16x8*)(G + (size_t)rq * 256 + colb + 8*g) = st;
                }
            }
        }
    }
}

// ---------- kernel 2: attention, one block per (r,h), K/V in LDS ----------
// Swapped QK^T (lane owns q-row), online exp (no max-sub), PV swapped
// (mfma(V,P)); 1/rowsum lane-local; epilogue single u16x8 (sigma layout).
__global__ __launch_bounds__(512) void attn_kernel(
    const unsigned short* __restrict__ Qa, const unsigned short* __restrict__ Ka,
    const unsigned short* __restrict__ Va, const unsigned short* __restrict__ G,
    const float* __restrict__ bt, unsigned short* __restrict__ og)
{
    __shared__ __align__(16) unsigned short Ks[256 * 40];  // [s][d'] pad 40
    __shared__ __align__(16) unsigned short Vs[32 * 264];  // [d][s'=slot] pad 264

    int rh = blockIdx.x;            // 0..1023
    int r = rh >> 3, h = rh & 7;
    int tid = threadIdx.x;          // 512 threads
    int w = tid >> 6, lane = tid & 63;
    int c = lane & 15, g = lane >> 4;
    size_t base = (size_t)rh * 8192;

    // stage K: plain padded copy (16B read / 16B write)
    #pragma unroll
    for (int j = 0; j < 2; ++j) {
        int idx8 = (tid + j*512) * 8;
        int s_ = idx8 >> 5, d_ = idx8 & 31;
        short8 v = *(const short8*)(Ka + base + idx8);
        *(short8*)(&Ks[s_*40 + d_]) = v;
    }
    // stage V: tau layout already equals PV slot order -> plain padded copy
    #pragma unroll
    for (int j = 0; j < 2; ++j) {
        int idx8 = (tid + j*512) * 8;
        int d_ = idx8 >> 8, s0 = idx8 & 255;
        short8 v = *(const short8*)(Va + base + idx8);
        *(short8*)(&Vs[d_*264 + s0]) = v;
    }
    __syncthreads();

    const float* bth = bt + (size_t)h * 65536;
    const float nrmv = 0.17677669529663687f;

    #pragma unroll 1
    for (int qq = 0; qq < 2; ++qq) {
        int qt = w*2 + qq;                 // 0..15
        int qrow = qt * 16;
        short8 qf = *(const short8*)(Qa + base + (size_t)(qrow + c)*32 + g*8);
        const float* btt = bth + (size_t)qt*4096 + (c*4 + g)*4;

        f32x4 o0 = 0.0f, o1 = 0.0f;
        float sum = 0.f;
        #pragma unroll
        for (int t = 0; t < 8; ++t) {
            int n0 = 2*t, n1 = 2*t + 1;
            short8 kf0 = *(const short8*)(&Ks[(n0*16 + c)*40 + g*8]);
            short8 kf1 = *(const short8*)(&Ks[(n1*16 + c)*40 + g*8]);
            f32x4 bv0 = *(const f32x4*)(btt + n0*256);
            f32x4 bv1 = *(const f32x4*)(btt + n1*256);
            f32x4 z = 0.0f;
            f32x4 s0 = __builtin_amdgcn_mfma_f32_16x16x32_bf16(kf0, qf, z, 0, 0, 0);
            f32x4 s1 = __builtin_amdgcn_mfma_f32_16x16x32_bf16(kf1, qf, z, 0, 0, 0);
            float e0 = __expf(fmaf(s0[0], nrmv, bv0[0]));
            float e1 = __expf(fmaf(s0[1], nrmv, bv0[1]));
            float e2 = __expf(fmaf(s0[2], nrmv, bv0[2]));
            float e3 = __expf(fmaf(s0[3], nrmv, bv0[3]));
            float e4 = __expf(fmaf(s1[0], nrmv, bv1[0]));
            float e5 = __expf(fmaf(s1[1], nrmv, bv1[1]));
            float e6 = __expf(fmaf(s1[2], nrmv, bv1[2]));
            float e7 = __expf(fmaf(s1[3], nrmv, bv1[3]));
            sum += ((e0+e1)+(e2+e3)) + ((e4+e5)+(e6+e7));
            u32x4 aw;
            aw[0] = pack2(e0, e1); aw[1] = pack2(e2, e3);
            aw[2] = pack2(e4, e5); aw[3] = pack2(e6, e7);
            short8 pfrag = __builtin_bit_cast(short8, aw);
            short8 va0 = *(const short8*)(&Vs[(c)*264      + t*32 + g*8]);
            short8 va1 = *(const short8*)(&Vs[(16 + c)*264 + t*32 + g*8]);
            o0 = __builtin_amdgcn_mfma_f32_16x16x32_bf16(va0, pfrag, o0, 0, 0, 0);
            o1 = __builtin_amdgcn_mfma_f32_16x16x32_bf16(va1, pfrag, o1, 0, 0, 0);
        }
        sum += __shfl_xor(sum, 16);
        sum += __shfl_xor(sum, 32);
        float inv = 1.0f / sum;

        // lane (c,g) holds O[q=qrow+c][d = n2*16+4g+i]; sigma(d) = 8g+4*n2+i
        size_t orow = ((size_t)(r*256 + qrow + c)) * 256 + h*32 + 8*g;
        u16x8 gv = *(const u16x8*)(G + orow);
        u16x8 st;
        #pragma unroll
        for (int i = 0; i < 4; ++i) {
            st[i]     = (unsigned short)bfbits(o0[i] * inv * bf2f(gv[i]));
            st[i + 4] = (unsigned short)bfbits(o1[i] * inv * bf2f(gv[i + 4]));
        }
        *(u16x8*)(og + orow) = st;
    }
}

// ---------- oproj K-loop (As: 64x256 swizzled tile, swapped) ----------
__device__ __forceinline__ void proj_mfma_loop_swap(
    const unsigned short* As, const unsigned short* Wt,
    int col0, int c, int g, f32x4 acc[4][4])
{
    short8 pb[4];
    #pragma unroll
    for (int n = 0; n < 4; ++n)
        pb[n] = *(const short8*)(Wt + (size_t)(col0 + n*16 + c) * 256 + g*8);

    #pragma unroll
    for (int step = 0; step < 8; ++step) {
        short8 b[4];
        #pragma unroll
        for (int n = 0; n < 4; ++n) b[n] = pb[n];
        if (step < 7) {
            int koff = (step + 1) * 32 + g * 8;
            #pragma unroll
            for (int n = 0; n < 4; ++n)
                pb[n] = *(const short8*)(Wt + (size_t)(col0 + n*16 + c) * 256 + koff);
        }
        short8 a[4];
        #pragma unroll
        for (int m = 0; m < 4; ++m) {
            int row = m * 16 + c;
            int off = row * 512 + ((step * 64 + g * 16) ^ ((row & 31) << 4));
            a[m] = *(const short8*)((const char*)As + off);
        }
        #pragma unroll
        for (int m = 0; m < 4; ++m)
            #pragma unroll
            for (int n = 0; n < 4; ++n)
                acc[m][n] = __builtin_amdgcn_mfma_f32_16x16x32_bf16(b[n], a[m], acc[m][n], 0, 0, 0);
    }
}

// ---------- kernel 3: output projection (LDS-staged og, swapped MFMA) ----------
__global__ __launch_bounds__(256) void oproj_kernel(
    const unsigned short* __restrict__ og, const unsigned short* __restrict__ wt_o,
    const float* __restrict__ bo, float* __restrict__ out)
{
    __shared__ __align__(16) unsigned short As[64 * 256];

    int row0 = blockIdx.x * 64;
    int tid = threadIdx.x;
    int lane = tid & 63;
    int c = lane & 15, g = lane >> 4;
    int col0 = (tid >> 6) * 64;

    // stage og tile (bf16 already), swizzled
    #pragma unroll
    for (int j = 0; j < 8; ++j) {
        int idx = tid * 8 + j * 2048;
        int row = idx >> 8;
        int colB = (idx & 255) * 2;
        short8 v = *(const short8*)(og + (size_t)(row0 + row) * 256 + (idx & 255));
        int off = row * 512 + (colB ^ ((row & 31) << 4));
        *(short8*)((char*)As + off) = v;
    }
    __syncthreads();

    f32x4 acc[4][4];
    #pragma unroll
    for (int m = 0; m < 4; ++m)
        #pragma unroll
        for (int n = 0; n < 4; ++n)
            acc[m][n] = 0.0f;

    proj_mfma_loop_swap(As, wt_o, col0, c, g, acc);

    #pragma unroll
    for (int n = 0; n < 4; ++n) {
        int colb = col0 + n * 16 + 4 * g;
        f32x4 bov = *(const f32x4*)(bo + colb);
        #pragma unroll
        for (int m = 0; m < 4; ++m) {
            int row = row0 + m * 16 + c;
            f32x4 st = acc[m][n] + bov;
            *(f32x4*)(out + (size_t)row * 256 + colb) = st;
        }
    }
}

extern "C" void kernel_launch(void* const* d_in, const int* in_sizes, int n_in,
                              void* d_out, int out_size, void* d_ws, size_t ws_size,
                              hipStream_t stream) {
    const float* qx   = (const float*)d_in[0];
    const float* kx   = (const float*)d_in[1];
    const float* vx   = (const float*)d_in[2];
    const float* bias = (const float*)d_in[3];
    const float* Wq   = (const float*)d_in[4];
    const float* Wk   = (const float*)d_in[5];
    const float* Wv   = (const float*)d_in[6];
    const float* Wo   = (const float*)d_in[7];
    const float* bo   = (const float*)d_in[8];
    const float* Wg   = (const float*)d_in[9];
    const float* bg   = (const float*)d_in[10];

    uint8_t* ws = (uint8_t*)d_ws;
    unsigned short* wt = (unsigned short*)ws;                         // 640 KB
    unsigned short* Qa = (unsigned short*)(ws + (1u<<20));
    unsigned short* Ka = (unsigned short*)(ws + (1u<<20) + 1u*(1u<<24));
    unsigned short* Va = (unsigned short*)(ws + (1u<<20) + 2u*(1u<<24));
    unsigned short* G  = (unsigned short*)(ws + (1u<<20) + 3u*(1u<<24));
    unsigned short* og = (unsigned short*)(ws + (1u<<20) + 4u*(1u<<24));
    float*          bt = (float*)        (ws + (1u<<20) + 5u*(1u<<24)); // 2 MB

    hipLaunchKernelGGL(prep_kernel, dim3(208), dim3(256), 0, stream,
                       Wq, Wk, Wv, Wg, Wo, wt, bias, bt);
    hipLaunchKernelGGL(proj_kernel, dim3(1536), dim3(256), 0, stream,
                       qx, kx, vx, bg, wt, Qa, Ka, Va, G);
    hipLaunchKernelGGL(attn_kernel, dim3(1024), dim3(512), 0, stream,
                       Qa, Ka, Va, G, bt, og);
    hipLaunchKernelGGL(oproj_kernel, dim3(512), dim3(256), 0, stream,
                       og, wt + 4*65536, bo, (float*)d_out);
}